// Round 11
// baseline (132.715 us; speedup 1.0000x reference)
//
#include <hip/hip_runtime.h>
#include <math.h>

#define KK 1024
#define DD 64
#define BS 65536              // 2048*32 rows
#define TM 32                 // rows per block
#define NBLK (BS/TM)          // 2048
#define NTHR 512
#define LN_2PI 1.8378770664093453f
#define DECAY 0.9f
#define APAD 136              // LDS row stride in halves (272B, 16B-aligned)

typedef _Float16 f16x8 __attribute__((ext_vector_type(8)));
typedef _Float16 f16x4 __attribute__((ext_vector_type(4)));
typedef float f32x16 __attribute__((ext_vector_type(16)));

// col-in-tile for accumulator register q (32x32 C/D mapping, rows now in lanes)
#define CLT(q) (((q) & 3) + 8 * ((q) >> 2))

// ws layout in FLOAT units:
//  [BH_OFF, +65536)  W_hi fp16 [16 kblk][1024 col][8 k]
//  [BL_OFF, +65536)  W_lo fp16 same layout
//  [C_OFF,  +1024)   c[k]
//  [SIG_OFF,+65536)  sigma[k][d] fp32
//  [RESP_OFF,+1024)  resp accumulator
#define BH_OFF   0
#define BL_OFF   65536
#define C_OFF    131072
#define SIG_OFF  (C_OFF + KK)
#define RESP_OFF (SIG_OFF + KK*DD)

__global__ __launch_bounds__(64) void prep_kernel(
    const float* __restrict__ mu, const float* __restrict__ log_sigma,
    float* __restrict__ ws) {
  int k = blockIdx.x;
  int d = threadIdx.x;
  float ls = log_sigma[k*DD + d];
  float m  = mu[k*DD + d];
  float iv = expf(-2.0f*ls);
  _Float16* Bh = (_Float16*)(ws + BH_OFF);
  _Float16* Bl = (_Float16*)(ws + BL_OFF);
  {
    float w0 = -0.5f*iv;                    // coeff of s^2 (dd = d)
    _Float16 hh = (_Float16)w0;
    Bh[((size_t)(d >> 3)*KK + k)*8 + (d & 7)] = hh;
    Bl[((size_t)(d >> 3)*KK + k)*8 + (d & 7)] = (_Float16)(w0 - (float)hh);
  }
  {
    float w1 = m*iv;                        // coeff of s (dd = 64+d)
    _Float16 hh = (_Float16)w1;
    int dd = 64 + d;
    Bh[((size_t)(dd >> 3)*KK + k)*8 + (dd & 7)] = hh;
    Bl[((size_t)(dd >> 3)*KK + k)*8 + (dd & 7)] = (_Float16)(w1 - (float)hh);
  }
  ws[SIG_OFF + k*DD + d] = expf(ls);
  float t1 = m*m*iv;
  float t2 = ls;
  #pragma unroll
  for (int off = 32; off; off >>= 1) {
    t1 += __shfl_xor(t1, off);
    t2 += __shfl_xor(t2, off);
  }
  if (d == 0) ws[C_OFF + k] = -0.5f*t1 - t2 - 32.0f*LN_2PI;
}

// R6 GEMM + SWAPPED MFMA OPERANDS: D = W_frag * S_frag puts slot-ROWS in
// lanes (j = lane&31) and cols in regs. Per lane: one row, 64 col-values in
// registers -> row max / exp-sum / argmax-scan are IN-LANE (no dependent
// cross-lane chains); only resp needs a cross-lane butterfly, and its 64
// reg-chains are independent (pipelined). c[k] is added post-GEMM from a
// broadcast LDS table (it is reg-indexed now, not lane-indexed).
__global__ __launch_bounds__(512, 4) void main_kernel(
    const float* __restrict__ slots, const float* __restrict__ mu,
    const float* __restrict__ z, const float* __restrict__ ws,
    float* __restrict__ out_slots, float* __restrict__ out_ll,
    float* __restrict__ resp_g) {
  __shared__ _Float16 Ah[TM][APAD];   // [row][dd]: dd<64 s^2 hi, dd>=64 s hi
  __shared__ _Float16 Al[TM][APAD];   // lo residuals
  __shared__ float cl[KK];            // c[k] broadcast table
  __shared__ float resl[KK];          // per-block resp
  __shared__ float mxl[TM][8];        // per-(row,wave) partial max
  __shared__ float sml[TM][8];        // per-(row,wave) partial exp-sum
  __shared__ float gm_l[TM];
  __shared__ float inv_l[TM];
  __shared__ int   am_l[TM];

  const int t    = threadIdx.x;
  const int lane = t & 63;
  const int w    = t >> 6;           // wave = 128-col group
  const int h    = lane >> 5;        // k half (0/1); also col sub-offset in D
  const int lc   = lane & 31;        // A-op row-in-tile AND D col(j) = slot row
  const int R0   = blockIdx.x * TM;

  const f16x8* BH = (const f16x8*)(ws + BH_OFF);
  const f16x8* BL = (const f16x8*)(ws + BL_OFF);
  const int col0 = (w << 7) + lc;                 // W-frag col of ct=0
  const f16x8* pH = BH + (size_t)h*KK + col0;     // + s*2*KK + ct*32
  const f16x8* pL = BL + (size_t)h*KK + col0;
  // D cols this lane owns: colbase + ct*32 + CLT(q)
  const int colbase = (w << 7) + 4*h;

  // ---- stage A (pre-split fp16 hi/lo) + c table ----
  {
    int row = t >> 4;                // 0..31
    int dp  = (t & 15) * 4;          // 0..60
    float4 v = *(const float4*)(slots + (size_t)(R0 + row)*DD + dp);
    float f[4] = {v.x, v.y, v.z, v.w};
    f16x4 sqh, sql, sh, sl;
    #pragma unroll
    for (int j = 0; j < 4; ++j) {
      float sq = f[j]*f[j];
      _Float16 h1 = (_Float16)sq;
      sqh[j] = h1; sql[j] = (_Float16)(sq - (float)h1);
      _Float16 h2 = (_Float16)f[j];
      sh[j] = h2;  sl[j]  = (_Float16)(f[j] - (float)h2);
    }
    *(f16x4*)&Ah[row][dp]      = sqh;
    *(f16x4*)&Al[row][dp]      = sql;
    *(f16x4*)&Ah[row][64 + dp] = sh;
    *(f16x4*)&Al[row][64 + dp] = sl;
  }
  cl[t]       = ws[C_OFF + t];
  cl[t + 512] = ws[C_OFF + t + 512];
  if (t < TM) am_l[t] = 0x7fffffff;
  __syncthreads();

  // ---- MFMA GEMM, swapped operands: acc[ct] = W * S ----
  f32x16 acc[4];
  #pragma unroll
  for (int ct = 0; ct < 4; ++ct) acc[ct] = (f32x16)(0.0f);

  #pragma unroll
  for (int s = 0; s < 8; ++s) {
    // S fragment (B-operand): lane holds row lc, k = s*16 + h*8 .. +8
    f16x8 ah = *(const f16x8*)&Ah[lc][s*16 + h*8];
    f16x8 al = *(const f16x8*)&Al[lc][s*16 + h*8];
    #pragma unroll
    for (int ct = 0; ct < 4; ++ct) {
      f16x8 bh = pH[(size_t)s*2*KK + ct*32];   // W fragment (A-operand)
      f16x8 bl = pL[(size_t)s*2*KK + ct*32];
      acc[ct] = __builtin_amdgcn_mfma_f32_32x32x16_f16(bh, ah, acc[ct], 0, 0, 0);
      acc[ct] = __builtin_amdgcn_mfma_f32_32x32x16_f16(bl, ah, acc[ct], 0, 0, 0);
      acc[ct] = __builtin_amdgcn_mfma_f32_32x32x16_f16(bh, al, acc[ct], 0, 0, 0);
    }
  }

  // ---- add c[k] (broadcast LDS reads, conflict-free) ----
  #pragma unroll
  for (int ct = 0; ct < 4; ++ct)
    #pragma unroll
    for (int q = 0; q < 16; ++q)
      acc[ct][q] += cl[colbase + ct*32 + CLT(q)];

  // ---- phase A: row max, in-lane tree + one shuffle ----
  {
    float m = acc[0][0];
    #pragma unroll
    for (int ct = 0; ct < 4; ++ct)
      #pragma unroll
      for (int q = 0; q < 16; ++q)
        m = fmaxf(m, acc[ct][q]);
    m = fmaxf(m, __shfl_xor(m, 32));    // combine the two col-halves (same row)
    if (lane < 32) mxl[lane][w] = m;    // lane == row
  }
  __syncthreads();

  // ---- phase B: combine 8 waves -> global max, ll ----
  if (t < TM) {
    float m = mxl[t][0];
    #pragma unroll
    for (int g = 1; g < 8; ++g) m = fmaxf(m, mxl[t][g]);
    gm_l[t] = m;
    out_ll[R0 + t] = m;
  }
  __syncthreads();

  // ---- phase C: in-lane argmax eq-scan (descending col) + exp + sum ----
  {
    const float gm = gm_l[lc];
    int cand = 0x7fffffff;
    #pragma unroll
    for (int ct = 3; ct >= 0; --ct)
      #pragma unroll
      for (int q = 15; q >= 0; --q)
        if (acc[ct][q] == gm) cand = colbase + ct*32 + CLT(q);
    if (cand != 0x7fffffff) atomicMin(&am_l[lc], cand);
    float ssum = 0.0f;
    #pragma unroll
    for (int ct = 0; ct < 4; ++ct)
      #pragma unroll
      for (int q = 0; q < 16; ++q) {
        float e = __expf(acc[ct][q] - gm);
        acc[ct][q] = e;
        ssum += e;
      }
    ssum += __shfl_xor(ssum, 32);
    if (lane < 32) sml[lane][w] = ssum;
  }
  __syncthreads();
  if (t < TM) {
    float s = 0.0f;
    #pragma unroll
    for (int g = 0; g < 8; ++g) s += sml[t][g];
    inv_l[t] = 1.0f / s;
  }
  __syncthreads();

  // ---- phase E: resp = sum over rows. Scale in-lane, butterfly over the
  //      32-lane group (64 independent reg-chains, pipelined), 2-lane write.
  {
    const float inv = inv_l[lc];
    #pragma unroll
    for (int ct = 0; ct < 4; ++ct)
      #pragma unroll
      for (int q = 0; q < 16; ++q)
        acc[ct][q] *= inv;
    #pragma unroll
    for (int off = 1; off < 32; off <<= 1) {
      #pragma unroll
      for (int ct = 0; ct < 4; ++ct)
        #pragma unroll
        for (int q = 0; q < 16; ++q)
          acc[ct][q] += __shfl_xor(acc[ct][q], off);
    }
    if (lc == 0) {                      // lanes 0 (h=0) and 32 (h=1)
      #pragma unroll
      for (int ct = 0; ct < 4; ++ct)
        #pragma unroll
        for (int q = 0; q < 16; ++q)
          resl[colbase + ct*32 + CLT(q)] = acc[ct][q];
    }
  }
  __syncthreads();
  atomicAdd(resp_g + t,       resl[t]);
  atomicAdd(resp_g + t + 512, resl[t + 512]);

  // ---- phase F: new_slots = mu[a] + sigma[a]*z ----
  {
    const int frow = t >> 4;
    const int fdp  = (t & 15) * 4;
    const int fa   = am_l[frow];
    float4 fz = *(const float4*)(z  + (size_t)(R0 + frow)*DD + fdp);
    float4 fm = *(const float4*)(mu + (size_t)fa*DD + fdp);
    float4 fs = *(const float4*)(ws + SIG_OFF + (size_t)fa*DD + fdp);
    float4 o;
    o.x = fmaf(fs.x, fz.x, fm.x); o.y = fmaf(fs.y, fz.y, fm.y);
    o.z = fmaf(fs.z, fz.z, fm.z); o.w = fmaf(fs.w, fz.w, fm.w);
    *(float4*)(out_slots + (size_t)(R0 + frow)*DD + fdp) = o;
  }
}

__device__ __forceinline__ float block_max_1024(float v, float* red) {
  #pragma unroll
  for (int off = 32; off; off >>= 1) v = fmaxf(v, __shfl_xor(v, off));
  int wave = threadIdx.x >> 6, lane = threadIdx.x & 63;
  if (lane == 0) red[wave] = v;
  __syncthreads();
  float m = red[0];
  #pragma unroll
  for (int w = 1; w < 16; ++w) m = fmaxf(m, red[w]);
  __syncthreads();
  return m;
}

__device__ __forceinline__ float block_sum_1024(float v, float* red) {
  #pragma unroll
  for (int off = 32; off; off >>= 1) v += __shfl_xor(v, off);
  int wave = threadIdx.x >> 6, lane = threadIdx.x & 63;
  if (lane == 0) red[wave] = v;
  __syncthreads();
  float s = 0.0f;
  #pragma unroll
  for (int w = 0; w < 16; ++w) s += red[w];
  __syncthreads();
  return s;
}

__global__ __launch_bounds__(1024) void finalize_kernel(
    const float* __restrict__ log_prior, const float* __restrict__ resp_g,
    float* __restrict__ out_prior) {
  __shared__ float red[16];
  int t = threadIdx.x;
  float lp = log_prior[t];
  float rs = resp_g[t];

  float m1 = block_max_1024(lp, red);
  float e1 = __expf(lp - m1);
  float s1 = block_sum_1024(e1, red);

  float m2 = block_max_1024(rs, red);
  float e2 = __expf(rs - m2);
  float s2 = block_sum_1024(e2, red);

  out_prior[t] = DECAY * (e1 / s1) + (1.0f - DECAY) * (e2 / s2);
}

extern "C" void kernel_launch(void* const* d_in, const int* in_sizes, int n_in,
                              void* d_out, int out_size, void* d_ws, size_t ws_size,
                              hipStream_t stream) {
  const float* slots     = (const float*)d_in[0];
  const float* mu        = (const float*)d_in[1];
  const float* log_sigma = (const float*)d_in[2];
  const float* log_prior = (const float*)d_in[3];
  const float* z         = (const float*)d_in[4];

  float* out       = (float*)d_out;
  float* out_slots = out;                       // [BS*DD]
  float* out_ll    = out + (size_t)BS*DD;       // [BS]
  float* out_prior = out + (size_t)BS*DD + BS;  // [KK]
  float* ws        = (float*)d_ws;

  hipMemsetAsync(ws + RESP_OFF, 0, KK*sizeof(float), stream);
  prep_kernel<<<KK, 64, 0, stream>>>(mu, log_sigma, ws);
  main_kernel<<<NBLK, NTHR, 0, stream>>>(slots, mu, z, ws, out_slots, out_ll,
                                         ws + RESP_OFF);
  finalize_kernel<<<1, 1024, 0, stream>>>(log_prior, ws + RESP_OFF, out_prior);
}